// Round 2
// baseline (892.093 us; speedup 1.0000x reference)
//
#include <hip/hip_runtime.h>
#include <hip/hip_bf16.h>
#include <stdint.h>

#define B_   64
#define T_   512
#define NIN_ 256
#define N_   512

typedef _Float16 half2_t __attribute__((ext_vector_type(2)));

#if defined(__has_builtin)
#if __has_builtin(__builtin_amdgcn_fdot2)
#define HAVE_FDOT2 1
#endif
#endif

__device__ __forceinline__ float dot2acc(unsigned int a, unsigned int b, float c) {
#ifdef HAVE_FDOT2
  return __builtin_amdgcn_fdot2(__builtin_bit_cast(half2_t, a),
                                __builtin_bit_cast(half2_t, b), c, false);
#else
  half2_t ha = __builtin_bit_cast(half2_t, a), hb = __builtin_bit_cast(half2_t, b);
  c += (float)ha[0] * (float)hb[0];
  c += (float)ha[1] * (float)hb[1];
  return c;
#endif
}

__device__ __forceinline__ float fast_tanh(float x) {
  float e = __expf(2.0f * x);
  return 1.0f - 2.0f / (e + 1.0f);
}

// ---------------- Phase 1: xp[b,t,n] = sum_c x[b,t,c] * Wih[n,c] -> out ----
__global__ __launch_bounds__(256) void xproj(const float* __restrict__ x,
                                             const float* __restrict__ Wih,
                                             float* __restrict__ out) {
  const int tid = threadIdx.x;
  const int bm = blockIdx.x;
  const int bn = blockIdx.y;
  const int tm = tid & 15;
  const int tn = tid >> 4;
  const int m0 = bm << 7;
  const int n0 = bn << 7;

  __shared__ float xt[32][132];
  __shared__ float wt[32][132];

  float acc[8][8];
#pragma unroll
  for (int i = 0; i < 8; ++i)
#pragma unroll
    for (int j = 0; j < 8; ++j) acc[i][j] = 0.f;

  for (int ko = 0; ko < NIN_; ko += 32) {
#pragma unroll
    for (int it = 0; it < 4; ++it) {
      const int fidx = it * 256 + tid;
      const int mm = fidx >> 3;
      const int k4 = (fidx & 7) << 2;
      const float4 vx = *(const float4*)(x + (size_t)(m0 + mm) * NIN_ + ko + k4);
      xt[k4 + 0][mm] = vx.x; xt[k4 + 1][mm] = vx.y;
      xt[k4 + 2][mm] = vx.z; xt[k4 + 3][mm] = vx.w;
      const float4 vw = *(const float4*)(Wih + (size_t)(n0 + mm) * NIN_ + ko + k4);
      wt[k4 + 0][mm] = vw.x; wt[k4 + 1][mm] = vw.y;
      wt[k4 + 2][mm] = vw.z; wt[k4 + 3][mm] = vw.w;
    }
    __syncthreads();
#pragma unroll 4
    for (int kk = 0; kk < 32; ++kk) {
      float a[8], b[8];
      *(float4*)&a[0] = *(const float4*)&xt[kk][8 * tm];
      *(float4*)&a[4] = *(const float4*)&xt[kk][8 * tm + 4];
      *(float4*)&b[0] = *(const float4*)&wt[kk][8 * tn];
      *(float4*)&b[4] = *(const float4*)&wt[kk][8 * tn + 4];
#pragma unroll
      for (int i = 0; i < 8; ++i)
#pragma unroll
        for (int j = 0; j < 8; ++j) acc[i][j] = fmaf(a[i], b[j], acc[i][j]);
    }
    __syncthreads();
  }

#pragma unroll
  for (int i = 0; i < 8; ++i) {
    float4 v0 = make_float4(acc[i][0], acc[i][1], acc[i][2], acc[i][3]);
    float4 v1 = make_float4(acc[i][4], acc[i][5], acc[i][6], acc[i][7]);
    float* p = out + (size_t)(m0 + 8 * tm + i) * N_ + n0 + 8 * tn;
    *(float4*)p = v0;
    *((float4*)p + 1) = v1;
  }
}

// ---------------- Phase 2: recurrent scan ---------------------------------
// 256 blocks x 448 threads. block = m*64+b. Waves 0-3 compute (lane = (neuron,
// k-half), 128 f16-pair weights in VGPR). Waves 4-6 are dedicated pollers:
// they spin on the 192 remote exchange slots CONCURRENTLY with compute, so
// the store->visibility latency of step t overlaps the dot product of step t.
// One __syncthreads per step; reductions via shfl; thp double-buffered.
__global__ __launch_bounds__(448, 2) void rnn_scan(const float* __restrict__ Whh,
                                                   float* __restrict__ out,
                                                   unsigned long long* __restrict__ ex) {
  const int blk = blockIdx.x;
  const int m = blk >> 6;        // slice 0..3 (128 neurons)
  const int b = blk & 63;        // batch
  const int tid = threadIdx.x;
  const int wv = tid >> 6;
  const int lane = tid & 63;

  __shared__ __align__(16) unsigned int thp[2][256];  // tanh(h) packed f16x2, dbuf

  float* outb = out + (size_t)b * T_ * N_;
  unsigned long long* exb = ex + (size_t)b * 2 * 256;

  // init thp[0] from h0 = out[b][0][:] (written by xproj; kernel boundary)
  if (tid < 256) {
    float2 h0 = *(const float2*)(outb + 2 * tid);
    half2_t hp;
    hp[0] = (_Float16)fast_tanh(h0.x);
    hp[1] = (_Float16)fast_tanh(h0.y);
    thp[0][tid] = __builtin_bit_cast(unsigned int, hp);
  }

  if (wv < 4) {
    // ---- compute role: cl in [0,256): neuron nn = cl>>1, k-half hh = cl&1
    const int cl = tid;
    const int nn = cl >> 1;
    const int hh = cl & 1;
    const int gn = m * 128 + nn;           // global neuron
    const bool even = (hh == 0);
    const bool q0 = ((cl & 3) == 0);
    const int pidx = m * 64 + (cl >> 2);   // own packed u32 slot (q0 lanes)

    unsigned int w[128];
    {
      const float* wr = Whh + (size_t)gn * N_ + hh * 256;
#pragma unroll
      for (int j = 0; j < 128; ++j) {
        half2_t h;
        h[0] = (_Float16)wr[2 * j];
        h[1] = (_Float16)wr[2 * j + 1];
        w[j] = __builtin_bit_cast(unsigned int, h);
      }
    }
    __syncthreads();   // weights loaded, thp[0] init visible

    for (int t = 1; t < T_; ++t) {
      // prefetch xp (only even lanes need it); overlaps the dot below
      float xp = 0.f;
      if (even) xp = outb[(size_t)t * N_ + gn];

      const uint4* tq = (const uint4*)&thp[(t - 1) & 1][hh * 128];
      float acc = 0.f;
#pragma unroll
      for (int j4 = 0; j4 < 32; ++j4) {
        uint4 tv = tq[j4];
        acc = dot2acc(w[4 * j4 + 0], tv.x, acc);
        acc = dot2acc(w[4 * j4 + 1], tv.y, acc);
        acc = dot2acc(w[4 * j4 + 2], tv.z, acc);
        acc = dot2acc(w[4 * j4 + 3], tv.w, acc);
      }
      // combine k-halves (adjacent lanes) -> full dot in both lanes
      float y = acc + __shfl_xor(acc, 1) + xp;
      float th = 0.f;
      if (even) th = fast_tanh(y);
      float thn = __shfl_xor(th, 2);       // neighbor neuron's tanh (even lanes)
      if (q0) {
        half2_t hp;
        hp[0] = (_Float16)th;
        hp[1] = (_Float16)thn;
        const unsigned int pk = __builtin_bit_cast(unsigned int, hp);
        thp[t & 1][pidx] = pk;
        // exchange store ASAP (peers' pollers are already spinning)
        __hip_atomic_store(&exb[(t & 1) * 256 + pidx],
                           ((unsigned long long)(unsigned int)t << 32) | pk,
                           __ATOMIC_RELAXED, __HIP_MEMORY_SCOPE_AGENT);
      }
      if (even) __builtin_nontemporal_store(y, &outb[(size_t)t * N_ + gn]);
      __syncthreads();   // publishes thp[t&1] (own + polled remote) for t+1
    }
  } else {
    // ---- poller role: waves 4..6, one remote u32 slot each (192 total)
    const int s = (wv - 4) * 64 + lane;          // 0..191
    const int pr = s + (s >= m * 64 ? 64 : 0);   // skip own slice's 64 slots
    __syncthreads();   // match compute pre-loop barrier

    for (int t = 1; t < T_; ++t) {
      if (t < T_ - 1) {
        // poll for tag t (arrives at end of everyone's step t); this spin
        // runs concurrently with the compute waves' step-t dot product.
        unsigned long long v;
        do {
          v = __hip_atomic_load(&exb[(t & 1) * 256 + pr], __ATOMIC_RELAXED,
                                __HIP_MEMORY_SCOPE_AGENT);
        } while ((unsigned int)(v >> 32) != (unsigned int)t);
        thp[t & 1][pr] = (unsigned int)v;
      }
      __syncthreads();
    }
  }
}

extern "C" void kernel_launch(void* const* d_in, const int* in_sizes, int n_in,
                              void* d_out, int out_size, void* d_ws, size_t ws_size,
                              hipStream_t stream) {
  const float* x   = (const float*)d_in[0];
  const float* Wih = (const float*)d_in[1];
  const float* Whh = (const float*)d_in[2];
  float* out = (float*)d_out;
  unsigned long long* ex = (unsigned long long*)d_ws;

  // exchange buffer: 64 batches x 2 slots x 256 pairs x 8B = 256 KiB
  hipMemsetAsync(d_ws, 0, (size_t)B_ * 2 * 256 * 8, stream);

  dim3 g1(256, 4);
  xproj<<<g1, 256, 0, stream>>>(x, Wih, out);
  rnn_scan<<<256, 448, 0, stream>>>(Whh, out, ex);
}